// Round 1
// baseline (83.066 us; speedup 1.0000x reference)
//
#include <hip/hip_runtime.h>
#include <math.h>

#define N3 65536
#define N4 16384
#define N5 4096
#define NTOT (N3 + N4 + N5)
#define M 128

__global__ __launch_bounds__(256) void fcos_fused_kernel(
    const float* __restrict__ locs3, const float* __restrict__ locs4,
    const float* __restrict__ locs5, const float* __restrict__ gt,
    const float* __restrict__ p3, const float* __restrict__ p4,
    const float* __restrict__ p5, float* __restrict__ out)
{
    __shared__ float sx0[M], sy0[M], sx1[M], sy1[M], sneg[M]; // sneg = 1e8 - area

    const int t = blockIdx.x * 256 + threadIdx.x;
    const int b = t / NTOT;          // uniform per block (NTOT % 256 == 0)
    const int n = t - b * NTOT;

    // Stage this batch's GT boxes into LDS (SoA; loop reads are lane-broadcast).
    const float* g = gt + b * (M * 5);
    for (int i = threadIdx.x; i < M; i += 256) {
        const float x0 = g[i * 5 + 0], y0 = g[i * 5 + 1];
        const float x1 = g[i * 5 + 2], y1 = g[i * 5 + 3];
        sx0[i] = x0; sy0[i] = y0; sx1[i] = x1; sy1[i] = y1;
        sneg[i] = 1e8f - (x1 - x0) * (y1 - y0);
    }
    __syncthreads();

    // Level dispatch — uniform per block (N3 and N3+N4 are multiples of 256).
    float stride, lo, hi, cx, cy;
    const float* pred;
    if (n < N3) {
        stride = 8.f;  lo = 0.f;   hi = 64.f;
        cx = locs3[n * 2]; cy = locs3[n * 2 + 1];
        pred = p3 + ((size_t)b * N3 + n) * 4;
    } else if (n < N3 + N4) {
        const int ln = n - N3;
        stride = 16.f; lo = 64.f;  hi = 128.f;
        cx = locs4[ln * 2]; cy = locs4[ln * 2 + 1];
        pred = p4 + ((size_t)b * N4 + ln) * 4;
    } else {
        const int ln = n - N3 - N4;
        stride = 32.f; lo = 128.f; hi = INFINITY;
        cx = locs5[ln * 2]; cy = locs5[ln * 2 + 1];
        pred = p5 + ((size_t)b * N5 + ln) * 4;
    }

    // Match loop: argmax of ok * (1e8 - area); strict '>' keeps the first
    // occurrence of the max, matching jnp.argmax tie-breaking.
    float best = 0.f;
    int bidx = 0;
#pragma unroll 4
    for (int i = 0; i < M; ++i) {
        const float l  = cx - sx0[i];
        const float tt = cy - sy0[i];
        const float r  = sx1[i] - cx;
        const float bb = sy1[i] - cy;
        const float pmin = fminf(fminf(l, tt), fminf(r, bb));
        const float pmax = fmaxf(fmaxf(l, tt), fmaxf(r, bb));
        const bool ok = (pmin > 0.f) && (pmax > lo) && (pmax < hi);
        const float mm = ok ? sneg[i] : 0.f;
        if (mm > best) { best = mm; bidx = i; }
    }

    float m0, m1, m2, m3;
    if (best < 1e-5f) {
        m0 = m1 = m2 = m3 = -1.f;
    } else {
        m0 = sx0[bidx]; m1 = sy0[bidx]; m2 = sx1[bidx]; m3 = sy1[bidx];
    }

    // Deltas (stride is a power of two -> reciprocal multiply is bit-exact).
    const float inv = 1.f / stride;
    float d0 = (cx - m0) * inv;
    float d1 = (cy - m1) * inv;
    float d2 = (m2 - cx) * inv;
    float d3 = (m3 - cy) * inv;
    const bool bg = fabsf(m0 + 1.f) < 1e-6f;
    if (bg) { d0 = d1 = d2 = d3 = -1.f; }

    // Centerness.
    const float lrmin = fminf(d0, d2), lrmax = fmaxf(d0, d2);
    const float tbmin = fminf(d1, d3), tbmax = fmaxf(d1, d3);
    const float ratio = fminf(lrmin, tbmin) / (fmaxf(lrmax, tbmax) + 1e-6f);
    float ctr = sqrtf(fmaxf(ratio, 0.f));
    if (d0 < 0.f) ctr = -1.f;

    // Decode predicted boxes.
    const float4 pr = *(const float4*)pred;
    const float dc0 = fmaxf(pr.x, 0.f), dc1 = fmaxf(pr.y, 0.f);
    const float dc2 = fmaxf(pr.z, 0.f), dc3 = fmaxf(pr.w, 0.f);
    const float ox1 = fmaxf(cx - dc0 * stride, 0.f);
    const float oy1 = fmaxf(cy - dc1 * stride, 0.f);
    const float ox2 = fmaxf(cx + dc2 * stride, 0.f);
    const float oy2 = fmaxf(cy + dc3 * stride, 0.f);

    float* o = out + (size_t)t * 9;
    o[0] = d0; o[1] = d1; o[2] = d2; o[3] = d3; o[4] = ctr;
    o[5] = ox1; o[6] = oy1; o[7] = ox2; o[8] = oy2;
}

extern "C" void kernel_launch(void* const* d_in, const int* in_sizes, int n_in,
                              void* d_out, int out_size, void* d_ws, size_t ws_size,
                              hipStream_t stream) {
    const float* locs3 = (const float*)d_in[0];
    const float* locs4 = (const float*)d_in[1];
    const float* locs5 = (const float*)d_in[2];
    const float* gt    = (const float*)d_in[3];
    const float* p3    = (const float*)d_in[4];
    const float* p4    = (const float*)d_in[5];
    const float* p5    = (const float*)d_in[6];
    float* out = (float*)d_out;

    const int total  = 2 * NTOT;        // 172032 threads, one per (b, n)
    const int blocks = total / 256;     // 672 blocks, all full
    fcos_fused_kernel<<<blocks, 256, 0, stream>>>(locs3, locs4, locs5, gt,
                                                  p3, p4, p5, out);
}

// Round 2
// 77.658 us; speedup vs baseline: 1.0696x; 1.0696x over previous
//
#include <hip/hip_runtime.h>
#include <math.h>

#define N3 65536
#define N4 16384
#define N5 4096
#define NTOT (N3 + N4 + N5)
#define M 128

// Per-level worker. LVL is compile-time so lo/hi/stride constants fold and the
// window test specializes:
//   LVL0: lo=0   -> pmax>lo implied by pmin>0        : okv = min(pmin, 64-pmax)
//   LVL1: full   : okv = min(pmin, pmax-64, 128-pmax)  (v_min3)
//   LVL2: hi=inf -> pmax<hi always true              : okv = min(pmin, pmax-128)
// okv > 0  <=>  (pmin>0) & (pmax>lo) & (pmax<hi), exactly (no FP reassociation
// across the comparison: a-b>0 <=> a>b for finite a,b).
template <int LVL>
__device__ __forceinline__ void process_level(
    const float* __restrict__ locs, const float* __restrict__ pred,
    int ln, int t,
    const float* sx0, const float* sy0, const float* sx1, const float* sy1,
    const float* sneg, float* __restrict__ out)
{
    const float stride = (LVL == 0) ? 8.f : (LVL == 1) ? 16.f : 32.f;
    const float inv    = 1.f / stride;   // power of two -> bit-exact vs divide
    const float cx = locs[ln * 2], cy = locs[ln * 2 + 1];

    // Argmax of ok*(1e8-area) with first-occurrence tie-break: strict '>' on q,
    // and the ok-select fused into the take condition (q>0 always, best>=0, so
    // "!ok -> mm=0 -> never beats best" is preserved).
    float best = 0.f;
    int bidx = 0;
#pragma unroll 8
    for (int i = 0; i < M; ++i) {
        const float l  = cx - sx0[i];
        const float tt = cy - sy0[i];
        const float r  = sx1[i] - cx;
        const float bb = sy1[i] - cy;
        const float pmin = fminf(fminf(l, tt), fminf(r, bb));
        const float pmax = fmaxf(fmaxf(l, tt), fmaxf(r, bb));
        float okv;
        if (LVL == 0)      okv = fminf(pmin, 64.f - pmax);
        else if (LVL == 1) okv = fminf(fminf(pmin, pmax - 64.f), 128.f - pmax);
        else               okv = fminf(pmin, pmax - 128.f);
        const float q = sneg[i];
        const bool take = (okv > 0.f) && (q > best);
        best = take ? q : best;
        bidx = take ? i : bidx;
    }

    float m0, m1, m2, m3;
    if (best < 1e-5f) {
        m0 = m1 = m2 = m3 = -1.f;
    } else {
        m0 = sx0[bidx]; m1 = sy0[bidx]; m2 = sx1[bidx]; m3 = sy1[bidx];
    }

    float d0 = (cx - m0) * inv;
    float d1 = (cy - m1) * inv;
    float d2 = (m2 - cx) * inv;
    float d3 = (m3 - cy) * inv;
    if (fabsf(m0 + 1.f) < 1e-6f) { d0 = d1 = d2 = d3 = -1.f; }

    const float lrmin = fminf(d0, d2), lrmax = fmaxf(d0, d2);
    const float tbmin = fminf(d1, d3), tbmax = fmaxf(d1, d3);
    const float ratio = fminf(lrmin, tbmin) / (fmaxf(lrmax, tbmax) + 1e-6f);
    float ctr = sqrtf(fmaxf(ratio, 0.f));
    if (d0 < 0.f) ctr = -1.f;

    const float4 pr = *(const float4*)pred;
    const float ox1 = fmaxf(cx - fmaxf(pr.x, 0.f) * stride, 0.f);
    const float oy1 = fmaxf(cy - fmaxf(pr.y, 0.f) * stride, 0.f);
    const float ox2 = fmaxf(cx + fmaxf(pr.z, 0.f) * stride, 0.f);
    const float oy2 = fmaxf(cy + fmaxf(pr.w, 0.f) * stride, 0.f);

    float* o = out + (size_t)t * 9;
    o[0] = d0; o[1] = d1; o[2] = d2; o[3] = d3; o[4] = ctr;
    o[5] = ox1; o[6] = oy1; o[7] = ox2; o[8] = oy2;
}

__global__ __launch_bounds__(256) void fcos_fused_kernel(
    const float* __restrict__ locs3, const float* __restrict__ locs4,
    const float* __restrict__ locs5, const float* __restrict__ gt,
    const float* __restrict__ p3, const float* __restrict__ p4,
    const float* __restrict__ p5, float* __restrict__ out)
{
    __shared__ float sx0[M], sy0[M], sx1[M], sy1[M], sneg[M]; // sneg = 1e8-area

    const int t = blockIdx.x * 256 + threadIdx.x;
    const int b = t / NTOT;          // uniform per block (NTOT % 256 == 0)
    const int n = t - b * NTOT;

    const float* g = gt + b * (M * 5);
    for (int i = threadIdx.x; i < M; i += 256) {
        const float x0 = g[i * 5 + 0], y0 = g[i * 5 + 1];
        const float x1 = g[i * 5 + 2], y1 = g[i * 5 + 3];
        sx0[i] = x0; sy0[i] = y0; sx1[i] = x1; sy1[i] = y1;
        sneg[i] = 1e8f - (x1 - x0) * (y1 - y0);
    }
    __syncthreads();

    // Level dispatch is block-uniform (N3 and N3+N4 are multiples of 256):
    // scalar branch, no divergence, and each arm gets folded constants.
    if (n < N3) {
        process_level<0>(locs3, p3 + ((size_t)b * N3 + n) * 4, n, t,
                         sx0, sy0, sx1, sy1, sneg, out);
    } else if (n < N3 + N4) {
        const int ln = n - N3;
        process_level<1>(locs4, p4 + ((size_t)b * N4 + ln) * 4, ln, t,
                         sx0, sy0, sx1, sy1, sneg, out);
    } else {
        const int ln = n - N3 - N4;
        process_level<2>(locs5, p5 + ((size_t)b * N5 + ln) * 4, ln, t,
                         sx0, sy0, sx1, sy1, sneg, out);
    }
}

extern "C" void kernel_launch(void* const* d_in, const int* in_sizes, int n_in,
                              void* d_out, int out_size, void* d_ws, size_t ws_size,
                              hipStream_t stream) {
    const float* locs3 = (const float*)d_in[0];
    const float* locs4 = (const float*)d_in[1];
    const float* locs5 = (const float*)d_in[2];
    const float* gt    = (const float*)d_in[3];
    const float* p3    = (const float*)d_in[4];
    const float* p4    = (const float*)d_in[5];
    const float* p5    = (const float*)d_in[6];
    float* out = (float*)d_out;

    const int total  = 2 * NTOT;        // 172032 threads, one per (b, n)
    const int blocks = total / 256;     // 672 full blocks
    fcos_fused_kernel<<<blocks, 256, 0, stream>>>(locs3, locs4, locs5, gt,
                                                  p3, p4, p5, out);
}

// Round 3
// 74.250 us; speedup vs baseline: 1.1187x; 1.0459x over previous
//
#include <hip/hip_runtime.h>
#include <math.h>

#define N3 65536
#define N4 16384
#define N5 4096
#define NTOT (N3 + N4 + N5)
#define M 128
#define MPAD (M + 4)

// Shared state: GT boxes compacted per (block-level, batch). Candidate filter:
// given pmin>0 (location strictly inside box), real arithmetic gives
//   max(w,h)/2 <= pmax < max(w,h).
// So a box is unmatchable at a level unless  lo < max(w,h) < 2*hi.  We keep
// a +/-0.25 margin (fp32 sub error at coord scale 2048 is ~1.2e-4), making the
// filter strictly conservative: every box that could pass the reference's ok
// test survives. Order-preserving compaction keeps jnp.argmax first-occurrence
// tie-breaking (dropped boxes only ever contribute mm=0, which never beats
// best=0 under strict '>').
template <int LVL>
__device__ __forceinline__ void run_level(
    const float* __restrict__ locs, const float* __restrict__ pred,
    const float* __restrict__ g,   // this batch's gt base (M x 5)
    int ln, int t, float* __restrict__ out,
    float* cx0, float* cy0, float* cx1, float* cy1, float* cq,
    int* s_w0, int* s_w1)
{
    const float stride = (LVL == 0) ? 8.f : (LVL == 1) ? 16.f : 32.f;
    const float inv    = 1.f / stride;           // pow2 -> bit-exact
    const float keep_lo = (LVL == 0) ? -1.f : (LVL == 1) ? 63.75f : 127.75f;
    const float keep_hi = (LVL == 0) ? 128.25f : (LVL == 1) ? 256.25f : 1e30f;

    const int tx = threadIdx.x;

    // ---- stage + filter + ordered compaction (threads 0..127, 2 waves) ----
    if (tx < M) {
        const float x0 = g[tx * 5 + 0], y0 = g[tx * 5 + 1];
        const float x1 = g[tx * 5 + 2], y1 = g[tx * 5 + 3];
        const float w = x1 - x0, h = y1 - y0;
        const float mx = fmaxf(w, h);
        const bool keep = (mx > keep_lo) && (mx < keep_hi);
        const unsigned long long mask = __ballot(keep);
        const int lane = tx & 63;
        const int before = __popcll(mask & ((1ull << lane) - 1ull));
        if (lane == 63) {
            if (tx < 64) *s_w0 = __popcll(mask);
            else         *s_w1 = __popcll(mask);
        }
        __syncthreads();               // all 256 threads reach this (see below)
        const int base = (tx < 64) ? 0 : *s_w0;
        if (keep) {
            const int pos = base + before;
            cx0[pos] = x0; cy0[pos] = y0; cx1[pos] = x1; cy1[pos] = y1;
            cq[pos]  = 1e8f - w * h;
        }
    } else {
        __syncthreads();               // matching barrier for threads 128..255
    }
    __syncthreads();
    const int cnt = *s_w0 + *s_w1;
    if (tx < 4) cq[cnt + tx] = 0.f;    // sentinel q=0: never beats best=0
    __syncthreads();
    const int cnt4 = (cnt + 3) & ~3;   // block-uniform loop bound

    // ---- per-location match over compacted candidates ----
    const float cx = locs[ln * 2], cy = locs[ln * 2 + 1];

    float best = 0.f;
    int bidx = 0;
    for (int i = 0; i < cnt4; i += 4) {
#pragma unroll
        for (int j = 0; j < 4; ++j) {
            const int k = i + j;
            const float l  = cx - cx0[k];
            const float tt = cy - cy0[k];
            const float r  = cx1[k] - cx;
            const float bb = cy1[k] - cy;
            const float pmin = fminf(fminf(l, tt), fminf(r, bb));
            const float pmax = fmaxf(fmaxf(l, tt), fmaxf(r, bb));
            float okv;
            if (LVL == 0)      okv = fminf(pmin, 64.f - pmax);
            else if (LVL == 1) okv = fminf(fminf(pmin, pmax - 64.f), 128.f - pmax);
            else               okv = fminf(pmin, pmax - 128.f);
            const float q = cq[k];
            const bool take = (okv > 0.f) && (q > best);
            best = take ? q : best;
            bidx = take ? k : bidx;
        }
    }

    float m0, m1, m2, m3;
    if (best < 1e-5f) {
        m0 = m1 = m2 = m3 = -1.f;
    } else {
        m0 = cx0[bidx]; m1 = cy0[bidx]; m2 = cx1[bidx]; m3 = cy1[bidx];
    }

    float d0 = (cx - m0) * inv;
    float d1 = (cy - m1) * inv;
    float d2 = (m2 - cx) * inv;
    float d3 = (m3 - cy) * inv;
    if (fabsf(m0 + 1.f) < 1e-6f) { d0 = d1 = d2 = d3 = -1.f; }

    const float lrmin = fminf(d0, d2), lrmax = fmaxf(d0, d2);
    const float tbmin = fminf(d1, d3), tbmax = fmaxf(d1, d3);
    const float ratio = fminf(lrmin, tbmin) / (fmaxf(lrmax, tbmax) + 1e-6f);
    float ctr = sqrtf(fmaxf(ratio, 0.f));
    if (d0 < 0.f) ctr = -1.f;

    const float4 pr = *(const float4*)pred;
    const float ox1 = fmaxf(cx - fmaxf(pr.x, 0.f) * stride, 0.f);
    const float oy1 = fmaxf(cy - fmaxf(pr.y, 0.f) * stride, 0.f);
    const float ox2 = fmaxf(cx + fmaxf(pr.z, 0.f) * stride, 0.f);
    const float oy2 = fmaxf(cy + fmaxf(pr.w, 0.f) * stride, 0.f);

    float* o = out + (size_t)t * 9;
    o[0] = d0; o[1] = d1; o[2] = d2; o[3] = d3; o[4] = ctr;
    o[5] = ox1; o[6] = oy1; o[7] = ox2; o[8] = oy2;
}

__global__ __launch_bounds__(256) void fcos_fused_kernel(
    const float* __restrict__ locs3, const float* __restrict__ locs4,
    const float* __restrict__ locs5, const float* __restrict__ gt,
    const float* __restrict__ p3, const float* __restrict__ p4,
    const float* __restrict__ p5, float* __restrict__ out)
{
    __shared__ float cx0[MPAD], cy0[MPAD], cx1[MPAD], cy1[MPAD], cq[MPAD];
    __shared__ int s_w0, s_w1;

    const int t = blockIdx.x * 256 + threadIdx.x;
    const int b = t / NTOT;          // block-uniform (NTOT % 256 == 0)
    const int n = t - b * NTOT;
    const float* g = gt + b * (M * 5);

    // Level is block-uniform too (N3, N3+N4 are multiples of 256).
    if (n < N3) {
        run_level<0>(locs3, p3 + ((size_t)b * N3 + n) * 4, g, n, t, out,
                     cx0, cy0, cx1, cy1, cq, &s_w0, &s_w1);
    } else if (n < N3 + N4) {
        const int ln = n - N3;
        run_level<1>(locs4, p4 + ((size_t)b * N4 + ln) * 4, g, ln, t, out,
                     cx0, cy0, cx1, cy1, cq, &s_w0, &s_w1);
    } else {
        const int ln = n - N3 - N4;
        run_level<2>(locs5, p5 + ((size_t)b * N5 + ln) * 4, g, ln, t, out,
                     cx0, cy0, cx1, cy1, cq, &s_w0, &s_w1);
    }
}

extern "C" void kernel_launch(void* const* d_in, const int* in_sizes, int n_in,
                              void* d_out, int out_size, void* d_ws, size_t ws_size,
                              hipStream_t stream) {
    const float* locs3 = (const float*)d_in[0];
    const float* locs4 = (const float*)d_in[1];
    const float* locs5 = (const float*)d_in[2];
    const float* gt    = (const float*)d_in[3];
    const float* p3    = (const float*)d_in[4];
    const float* p4    = (const float*)d_in[5];
    const float* p5    = (const float*)d_in[6];
    float* out = (float*)d_out;

    const int total  = 2 * NTOT;        // 172032 threads, one per (b, n)
    const int blocks = total / 256;     // 672 full blocks
    fcos_fused_kernel<<<blocks, 256, 0, stream>>>(locs3, locs4, locs5, gt,
                                                  p3, p4, p5, out);
}